// Round 5
// baseline (816.079 us; speedup 1.0000x reference)
//
#include <hip/hip_runtime.h>
#include <cstdint>
#include <cstddef>

// ---------------------------------------------------------------------------
// Transformer block, MI355X bf16 MFMA implementation.
// R5 = R4 + V^T row stride padded 2048 -> 2176 elements (breaks the 4 KB
// power-of-2 L2-channel alias that serialized every flash variant), diagonal
// subtile peeled, main loop unrolled x2. GEMMs unchanged.
// ---------------------------------------------------------------------------

typedef unsigned short u16;
typedef __attribute__((ext_vector_type(8))) __bf16 bf16x8;   // MFMA A/B frag K=32
typedef __attribute__((ext_vector_type(4))) short s16x4;     // MFMA A/B frag K=16
typedef __attribute__((ext_vector_type(4))) float f32x4;     // MFMA C/D frag

#if defined(__has_builtin)
#if __has_builtin(__builtin_amdgcn_global_load_lds)
#define HAS_GLL 1
#endif
#endif

// attention scale 1/sqrt(64) folded with log2(e) so softmax runs in exp2 domain
#define QSCALE 0.18033688011112042f
#define VTS 2176   // V^T row stride in elements (4352 B = 4096+256: channel-spread)

__device__ __forceinline__ u16 f2bf(float f) {
  union { float f; unsigned int u; } c; c.f = f;
  unsigned int u = c.u;
  u += 0x7FFFu + ((u >> 16) & 1u);   // round-to-nearest-even
  return (u16)(u >> 16);
}
__device__ __forceinline__ u16 f2bf_fast(float f) {   // round-half-up, 2 insts
  union { float f; unsigned int u; } c; c.f = f;
  return (u16)((c.u + 0x8000u) >> 16);
}

// K=16 bf16 MFMA (v_mfma_f32_16x16x16_bf16). Device-only; host sees a stub.
__device__ __forceinline__ f32x4 mfma_pv(s16x4 a, s16x4 b, f32x4 c) {
#if defined(__HIP_DEVICE_COMPILE__)
#if defined(__has_builtin) && __has_builtin(__builtin_amdgcn_mfma_f32_16x16x16bf16_1k)
  return __builtin_amdgcn_mfma_f32_16x16x16bf16_1k(a, b, c, 0, 0, 0);
#else
  f32x4 d;
  asm volatile("v_mfma_f32_16x16x16_bf16 %0, %1, %2, %3"
               : "=v"(d) : "v"(a), "v"(b), "v"(c));
  return d;
#endif
#else
  (void)a; (void)b;
  return c;   // host stub, never executed
#endif
}

// async 16B/lane global->LDS stage; l must be wave-uniform, lane i lands at l+16*i
__device__ __forceinline__ void stage16(const u16* g, u16* l, int lane) {
#ifdef HAS_GLL
  __builtin_amdgcn_global_load_lds(
      (const __attribute__((address_space(1))) uint32_t*)(g),
      (__attribute__((address_space(3))) uint32_t*)(l), 16, 0, 0);
#else
  *(int4*)(l + lane * 8) = *(const int4*)g;
#endif
}

// ---------------- LayerNorm: fp32 [rows][1024] -> bf16 [rows][1024] --------
__global__ __launch_bounds__(256) void ln_k(const float* __restrict__ x,
                                            const float* __restrict__ g,
                                            const float* __restrict__ be,
                                            u16* __restrict__ out) {
  const int row = blockIdx.x;
  const int t = threadIdx.x;
  const float4 v = ((const float4*)(x + (size_t)row * 1024))[t];
  float s = v.x + v.y + v.z + v.w;
  float s2 = v.x * v.x + v.y * v.y + v.z * v.z + v.w * v.w;
#pragma unroll
  for (int off = 32; off > 0; off >>= 1) {
    s += __shfl_down(s, off);
    s2 += __shfl_down(s2, off);
  }
  __shared__ float red[8];
  if ((t & 63) == 0) { red[t >> 6] = s; red[4 + (t >> 6)] = s2; }
  __syncthreads();
  const float ts = red[0] + red[1] + red[2] + red[3];
  const float ts2 = red[4] + red[5] + red[6] + red[7];
  const float mu = ts * (1.0f / 1024.0f);
  const float var = ts2 * (1.0f / 1024.0f) - mu * mu;
  const float rstd = rsqrtf(var + 1e-5f);
  const float4 gv = ((const float4*)g)[t];
  const float4 bv = ((const float4*)be)[t];
  u16* op = out + (size_t)row * 1024 + t * 4;
  op[0] = f2bf((v.x - mu) * rstd * gv.x + bv.x);
  op[1] = f2bf((v.y - mu) * rstd * gv.y + bv.y);
  op[2] = f2bf((v.z - mu) * rstd * gv.z + bv.z);
  op[3] = f2bf((v.w - mu) * rstd * gv.w + bv.w);
}

// ------------- batched transpose fp32 [b][R][C] -> bf16 [b][C][R] ----------
__global__ __launch_bounds__(256) void transpose_k(const float* __restrict__ in,
                                                   u16* __restrict__ out,
                                                   int R, int Cc) {
  __shared__ float tile[32][33];
  const size_t base = (size_t)blockIdx.z * R * Cc;
  const int r0 = blockIdx.x * 32, c0 = blockIdx.y * 32;
  const int tx = threadIdx.x & 31, ty = threadIdx.x >> 5;
  const float* ip = in + base;
  u16* op = out + base;
#pragma unroll
  for (int i = 0; i < 32; i += 8)
    tile[ty + i][tx] = ip[(size_t)(r0 + ty + i) * Cc + c0 + tx];
  __syncthreads();
#pragma unroll
  for (int i = 0; i < 32; i += 8)
    op[(size_t)(c0 + ty + i) * R + r0 + tx] = f2bf(tile[tx][ty + i]);
}

// ---------------- GEMM: C[M][N] = A[M][K] * Bt[N][K]^T, epilogues ----------
// MODE 0: scatter to q[B,H,T,64] (pre-scaled), k[B,H,T,64], v_t[B,H,64,VTS]
// MODE 1: out0(f32) = acc + bias[n] + resid[m][n]      (Wo proj + residual)
// MODE 2: out0(bf16) = relu(acc + bias[n])             (MLP up)
// MODE 3: out0(f32) = acc + bias[n] + resid[m][n]      (MLP down + residual)
template <int MODE>
__global__ __launch_bounds__(256, 3) void gemm_k(
    const u16* __restrict__ A, const u16* __restrict__ Bt,
    const float* __restrict__ bias, const float* __restrict__ resid,
    void* __restrict__ out0, void* __restrict__ out1, void* __restrict__ out2,
    int M, int N, int K) {
  __shared__ u16 As[128 * 32];   // unpadded: required by global_load_lds layout
  __shared__ u16 Bs[128 * 32];
  const int tid = threadIdx.x;
  const int lane = tid & 63;
  const int w = tid >> 6;
  const int wm = w & 1, wn = w >> 1;        // 2x2 wave grid, 64x64 per wave
  const int l15 = lane & 15, lq = lane >> 4;
  const int m0 = blockIdx.x * 128, n0 = blockIdx.y * 128;
  const int srow = lane >> 2, scol = (lane & 3) * 8;

  f32x4 acc[4][4] = {};

  // wave w stages As rows [w*32, w*32+32) and Bs rows [w*32, w*32+32)
  const u16* gA0 = A  + (size_t)(m0 + w * 32 + srow) * K + scol;
  const u16* gA1 = gA0 + (size_t)16 * K;
  const u16* gB0 = Bt + (size_t)(n0 + w * 32 + srow) * K + scol;
  const u16* gB1 = gB0 + (size_t)16 * K;
  u16* lA0 = &As[(w * 32) * 32];
  u16* lA1 = &As[(w * 32 + 16) * 32];
  u16* lB0 = &Bs[(w * 32) * 32];
  u16* lB1 = &Bs[(w * 32 + 16) * 32];

  for (int k0 = 0; k0 < K; k0 += 32) {
    __syncthreads();
    stage16(gA0 + k0, lA0, lane);
    stage16(gA1 + k0, lA1, lane);
    stage16(gB0 + k0, lB0, lane);
    stage16(gB1 + k0, lB1, lane);
    __syncthreads();   // drains vmcnt: staged data visible
    bf16x8 af[4], bfr[4];
#pragma unroll
    for (int i = 0; i < 4; ++i)
      af[i] = *(const bf16x8*)&As[(wm * 64 + i * 16 + l15) * 32 + lq * 8];
#pragma unroll
    for (int j = 0; j < 4; ++j)
      bfr[j] = *(const bf16x8*)&Bs[(wn * 64 + j * 16 + l15) * 32 + lq * 8];
#pragma unroll
    for (int i = 0; i < 4; ++i)
#pragma unroll
      for (int j = 0; j < 4; ++j)
        acc[i][j] = __builtin_amdgcn_mfma_f32_16x16x32_bf16(af[i], bfr[j], acc[i][j], 0, 0, 0);
  }

#pragma unroll
  for (int i = 0; i < 4; ++i) {
    const int mbase = m0 + wm * 64 + i * 16 + lq * 4;   // C/D row = lq*4+r
#pragma unroll
    for (int j = 0; j < 4; ++j) {
      const int ncol = n0 + wn * 64 + j * 16 + l15;     // C/D col = l15
#pragma unroll
      for (int r = 0; r < 4; ++r) {
        const float v = acc[i][j][r];
        const int m = mbase + r;
        if (MODE == 0) {
          const int which = ncol >> 10;
          const int hh = (ncol >> 6) & 15;
          const int dd = ncol & 63;
          const int bb = m >> 11;
          const int tt = m & 2047;
          if (which == 0)   // q: fold attention scale * log2(e)
            ((u16*)out0)[(((size_t)(bb * 16 + hh) * 2048 + tt) << 6) + dd] = f2bf(v * QSCALE);
          else if (which == 1)
            ((u16*)out1)[(((size_t)(bb * 16 + hh) * 2048 + tt) << 6) + dd] = f2bf(v);
          else
            ((u16*)out2)[((size_t)(bb * 16 + hh) * 64 + dd) * VTS + tt] = f2bf(v);
        } else if (MODE == 1 || MODE == 3) {
          ((float*)out0)[(size_t)m * N + ncol] =
              v + bias[ncol] + resid[(size_t)m * N + ncol];
        } else {
          const float t2 = v + bias[ncol];
          ((u16*)out0)[(size_t)m * N + ncol] = f2bf(t2 > 0.0f ? t2 : 0.0f);
        }
      }
    }
  }
}

// ---------------- causal flash attention (shuffle/barrier/LDS-free) --------
// q (pre-scaled by QSCALE, exp2 domain), k: [BH][2048][64] bf16
// vt: [BH][64][VTS] bf16 (V transposed, padded stride). attn: [B][2048][1024].
// Block = (bh, 64 Q rows) = 4 fully independent waves, 16 Q rows each.
// S^T = K·Q^T: C/D layout of S^T IS the K=16 B-frag layout, so P feeds
// O^T = V^T·P^T with zero cross-lane movement. No max-tracking (scores
// bounded, diagonal guarantees l>=1).
__global__ __launch_bounds__(256) void flash_k(const u16* __restrict__ q,
                                               const u16* __restrict__ k,
                                               const u16* __restrict__ vt,
                                               u16* __restrict__ attn) {
  const int bh = blockIdx.x;                 // XCD affinity: bh%8
  const int qblk = 31 - blockIdx.y;          // longest blocks dispatch first
  const int bb = bh >> 4, hh = bh & 15;
  const int tid = threadIdx.x;
  const int lane = tid & 63, wid = tid >> 6;
  const int l15 = lane & 15, lq = lane >> 4;
  const int q0w = qblk * 64 + wid * 16;      // this wave's Q-row base

  // Q B-frags (n = qrow = l15): Q[q0w+l15][lq*8 .. +7], [+32 ..]
  const u16* qrow = q + ((size_t)bh * 2048 + q0w + l15) * 64 + lq * 8;
  const bf16x8 qb0 = *(const bf16x8*)qrow;
  const bf16x8 qb1 = *(const bf16x8*)(qrow + 32);

  // K A-frag base (m = j_local = l15): K[j0+l15][lq*8 .. +7]
  const u16* kbase = k + ((size_t)bh * 2048 + l15) * 64 + lq * 8;
  // V^T A-frag base (m = d_local = l15, K=16: k = lq*4+i)
  const u16* vbase = vt + ((size_t)bh * 64 + l15) * VTS + lq * 4;

  f32x4 o[4] = {};    // o[dt]: row = d_local = lq*4+r, col = qrow = l15
  float l_acc = 0.0f; // per-lane partial of row l15's softmax denominator

  // ---- main loop: all full (unmasked) subtiles ----
#pragma unroll 2
  for (int j0 = 0; j0 < q0w; j0 += 16) {
    const u16* kp = kbase + (size_t)j0 * 64;
    f32x4 st = {};
    st = __builtin_amdgcn_mfma_f32_16x16x32_bf16(*(const bf16x8*)kp, qb0, st, 0, 0, 0);
    st = __builtin_amdgcn_mfma_f32_16x16x32_bf16(*(const bf16x8*)(kp + 32), qb1, st, 0, 0, 0);

    float p0 = exp2f(st[0]), p1 = exp2f(st[1]);
    float p2 = exp2f(st[2]), p3 = exp2f(st[3]);
    l_acc += (p0 + p1) + (p2 + p3);
    s16x4 pf;
    pf[0] = (short)f2bf_fast(p0); pf[1] = (short)f2bf_fast(p1);
    pf[2] = (short)f2bf_fast(p2); pf[3] = (short)f2bf_fast(p3);

#pragma unroll
    for (int dt = 0; dt < 4; ++dt) {
      const s16x4 va = *(const s16x4*)(vbase + (size_t)dt * 16 * VTS + j0);
      o[dt] = mfma_pv(va, pf, o[dt]);
    }
  }

  // ---- diagonal subtile (j0 == q0w), causal-masked ----
  {
    const int j0 = q0w;
    const u16* kp = kbase + (size_t)j0 * 64;
    f32x4 st = {};
    st = __builtin_amdgcn_mfma_f32_16x16x32_bf16(*(const bf16x8*)kp, qb0, st, 0, 0, 0);
    st = __builtin_amdgcn_mfma_f32_16x16x32_bf16(*(const bf16x8*)(kp + 32), qb1, st, 0, 0, 0);
#pragma unroll
    for (int r = 0; r < 4; ++r)
      if (lq * 4 + r > l15) st[r] = -1e30f;

    float p0 = exp2f(st[0]), p1 = exp2f(st[1]);
    float p2 = exp2f(st[2]), p3 = exp2f(st[3]);
    l_acc += (p0 + p1) + (p2 + p3);
    s16x4 pf;
    pf[0] = (short)f2bf_fast(p0); pf[1] = (short)f2bf_fast(p1);
    pf[2] = (short)f2bf_fast(p2); pf[3] = (short)f2bf_fast(p3);

#pragma unroll
    for (int dt = 0; dt < 4; ++dt) {
      const s16x4 va = *(const s16x4*)(vbase + (size_t)dt * 16 * VTS + j0);
      o[dt] = mfma_pv(va, pf, o[dt]);
    }
  }

  // row-sum: lanes sharing l15 differ in lane bits 4-5
  l_acc += __shfl_xor(l_acc, 16);
  l_acc += __shfl_xor(l_acc, 32);
  const float rl = 1.0f / l_acc;

  // write: row i = q0w+l15; d = dt*16 + lq*4 + r  (4 consecutive bf16 per dt)
  u16* op = attn + ((size_t)bb * 2048 + q0w + l15) * 1024 + hh * 64 + lq * 4;
#pragma unroll
  for (int dt = 0; dt < 4; ++dt) {
    union { s16x4 v; u16 a[4]; } pk;
#pragma unroll
    for (int r = 0; r < 4; ++r) pk.a[r] = f2bf(o[dt][r] * rl);
    *(s16x4*)(op + dt * 16) = pk.v;
  }
}

// ---------------------------------------------------------------------------
extern "C" void kernel_launch(void* const* d_in, const int* in_sizes, int n_in,
                              void* d_out, int out_size, void* d_ws, size_t ws_size,
                              hipStream_t stream) {
  const float* x   = (const float*)d_in[0];
  const float* Wq  = (const float*)d_in[1];
  const float* Wk  = (const float*)d_in[2];
  const float* Wv  = (const float*)d_in[3];
  const float* Wo  = (const float*)d_in[4];
  const float* bo  = (const float*)d_in[5];
  const float* W1  = (const float*)d_in[6];
  const float* b1  = (const float*)d_in[7];
  const float* W2  = (const float*)d_in[8];
  const float* b2  = (const float*)d_in[9];
  const float* g1  = (const float*)d_in[10];
  const float* be1 = (const float*)d_in[11];
  const float* g2  = (const float*)d_in[12];
  const float* be2 = (const float*)d_in[13];
  float* out = (float*)d_out;

  char* ws = (char*)d_ws;
  u16* Wqkv_t = (u16*)(ws + 0);            //  6 MiB  [3072][1024]
  u16* Wo_t   = (u16*)(ws + 6291456);      //  2 MiB  [1024][1024]
  u16* W1_t   = (u16*)(ws + 8388608);      //  8 MiB  [4096][1024]
  u16* W2_t   = (u16*)(ws + 16777216);     //  8 MiB  [1024][4096]
  u16* hbuf   = (u16*)(ws + 25165824);     // 16 MiB  [8192][1024] (LN out, reused)
  float* x2   = (float*)(ws + 41943040);   // 32 MiB  [8192][1024] f32 mid residual
  u16* vtb    = (u16*)(ws + 41943040);     // 17.8 MB [64][64][VTS], overlaps x2:
                                           //   vtb dead before gemm<1> writes x2
  u16* qb     = (u16*)(ws + 75497472);     // 16 MiB  [64][2048][64]
  u16* kb     = (u16*)(ws + 92274688);     // 16 MiB
  u16* attnb  = (u16*)(ws + 109051904);    // 16 MiB  [8192][1024]
  u16* a1     = (u16*)(ws + 75497472);     // 64 MiB  [8192][4096], reuses qb/kb/attnb

  dim3 blk(256);

  // weights -> bf16, transposed to [N][K]
  transpose_k<<<dim3(32, 2, 16),  blk, 0, stream>>>(Wq, Wqkv_t,            1024, 64);
  transpose_k<<<dim3(32, 2, 16),  blk, 0, stream>>>(Wk, Wqkv_t + 1048576,  1024, 64);
  transpose_k<<<dim3(32, 2, 16),  blk, 0, stream>>>(Wv, Wqkv_t + 2097152,  1024, 64);
  transpose_k<<<dim3(32, 32, 1),  blk, 0, stream>>>(Wo, Wo_t,              1024, 1024);
  transpose_k<<<dim3(32, 128, 1), blk, 0, stream>>>(W1, W1_t,              1024, 4096);
  transpose_k<<<dim3(128, 32, 1), blk, 0, stream>>>(W2, W2_t,              4096, 1024);

  // LN1
  ln_k<<<8192, blk, 0, stream>>>(x, g1, be1, hbuf);
  // QKV projection with scatter epilogue (q pre-scaled)
  gemm_k<0><<<dim3(64, 24), blk, 0, stream>>>(hbuf, Wqkv_t, nullptr, nullptr,
                                              qb, kb, vtb, 8192, 3072, 1024);
  // causal flash attention
  flash_k<<<dim3(64, 32), blk, 0, stream>>>(qb, kb, vtb, attnb);
  // output projection + bias + residual -> x2 (f32; overwrites dead vtb)
  gemm_k<1><<<dim3(64, 8), blk, 0, stream>>>(attnb, Wo_t, bo, x,
                                             x2, nullptr, nullptr, 8192, 1024, 1024);
  // LN2
  ln_k<<<8192, blk, 0, stream>>>(x2, g2, be2, hbuf);
  // MLP up + relu
  gemm_k<2><<<dim3(64, 32), blk, 0, stream>>>(hbuf, W1_t, b1, nullptr,
                                              a1, nullptr, nullptr, 8192, 4096, 1024);
  // MLP down + bias + residual -> out (f32)
  gemm_k<3><<<dim3(64, 8), blk, 0, stream>>>(a1, W2_t, b2, x2,
                                             out, nullptr, nullptr, 8192, 1024, 4096);
}

// Round 7
// 535.874 us; speedup vs baseline: 1.5229x; 1.5229x over previous
//
#include <hip/hip_runtime.h>
#include <cstdint>
#include <cstddef>

// ---------------------------------------------------------------------------
// Transformer block, MI355X bf16 MFMA implementation.
// R7 = R6 with fragment-order strides FIXED:
//   K'[bh][jg][kk][lane]x8:  bh*131072 + jg*1024 + kk*512 + lane*8
//   V'[bh][dt][jg][lane]x4:  bh*131072 + dt*32768 + jg*256 + lane*4
// (R6 doubled both jg strides -> buffers self-overwrote -> absmax 2.19.)
// Flash hot loop: every K/V load is one contiguous 1KB/512B wave transaction.
// ---------------------------------------------------------------------------

typedef unsigned short u16;
typedef __attribute__((ext_vector_type(8))) __bf16 bf16x8;   // MFMA A/B frag K=32
typedef __attribute__((ext_vector_type(4))) short s16x4;     // MFMA A/B frag K=16
typedef __attribute__((ext_vector_type(4))) float f32x4;     // MFMA C/D frag

#if defined(__has_builtin)
#if __has_builtin(__builtin_amdgcn_global_load_lds)
#define HAS_GLL 1
#endif
#endif

// attention scale 1/sqrt(64) folded with log2(e) so softmax runs in exp2 domain
#define QSCALE 0.18033688011112042f

__device__ __forceinline__ u16 f2bf(float f) {
  union { float f; unsigned int u; } c; c.f = f;
  unsigned int u = c.u;
  u += 0x7FFFu + ((u >> 16) & 1u);   // round-to-nearest-even
  return (u16)(u >> 16);
}
__device__ __forceinline__ u16 f2bf_fast(float f) {   // round-half-up, 2 insts
  union { float f; unsigned int u; } c; c.f = f;
  return (u16)((c.u + 0x8000u) >> 16);
}

// K=16 bf16 MFMA (v_mfma_f32_16x16x16_bf16). Device-only; host sees a stub.
__device__ __forceinline__ f32x4 mfma_pv(s16x4 a, s16x4 b, f32x4 c) {
#if defined(__HIP_DEVICE_COMPILE__)
#if defined(__has_builtin) && __has_builtin(__builtin_amdgcn_mfma_f32_16x16x16bf16_1k)
  return __builtin_amdgcn_mfma_f32_16x16x16bf16_1k(a, b, c, 0, 0, 0);
#else
  f32x4 d;
  asm volatile("v_mfma_f32_16x16x16_bf16 %0, %1, %2, %3"
               : "=v"(d) : "v"(a), "v"(b), "v"(c));
  return d;
#endif
#else
  (void)a; (void)b;
  return c;   // host stub, never executed
#endif
}

// async 16B/lane global->LDS stage; l must be wave-uniform, lane i lands at l+16*i
__device__ __forceinline__ void stage16(const u16* g, u16* l, int lane) {
#ifdef HAS_GLL
  __builtin_amdgcn_global_load_lds(
      (const __attribute__((address_space(1))) uint32_t*)(g),
      (__attribute__((address_space(3))) uint32_t*)(l), 16, 0, 0);
#else
  *(int4*)(l + lane * 8) = *(const int4*)g;
#endif
}

// ---------------- LayerNorm: fp32 [rows][1024] -> bf16 [rows][1024] --------
__global__ __launch_bounds__(256) void ln_k(const float* __restrict__ x,
                                            const float* __restrict__ g,
                                            const float* __restrict__ be,
                                            u16* __restrict__ out) {
  const int row = blockIdx.x;
  const int t = threadIdx.x;
  const float4 v = ((const float4*)(x + (size_t)row * 1024))[t];
  float s = v.x + v.y + v.z + v.w;
  float s2 = v.x * v.x + v.y * v.y + v.z * v.z + v.w * v.w;
#pragma unroll
  for (int off = 32; off > 0; off >>= 1) {
    s += __shfl_down(s, off);
    s2 += __shfl_down(s2, off);
  }
  __shared__ float red[8];
  if ((t & 63) == 0) { red[t >> 6] = s; red[4 + (t >> 6)] = s2; }
  __syncthreads();
  const float ts = red[0] + red[1] + red[2] + red[3];
  const float ts2 = red[4] + red[5] + red[6] + red[7];
  const float mu = ts * (1.0f / 1024.0f);
  const float var = ts2 * (1.0f / 1024.0f) - mu * mu;
  const float rstd = rsqrtf(var + 1e-5f);
  const float4 gv = ((const float4*)g)[t];
  const float4 bv = ((const float4*)be)[t];
  u16* op = out + (size_t)row * 1024 + t * 4;
  op[0] = f2bf((v.x - mu) * rstd * gv.x + bv.x);
  op[1] = f2bf((v.y - mu) * rstd * gv.y + bv.y);
  op[2] = f2bf((v.z - mu) * rstd * gv.z + bv.z);
  op[3] = f2bf((v.w - mu) * rstd * gv.w + bv.w);
}

// ------------- batched transpose fp32 [b][R][C] -> bf16 [b][C][R] ----------
__global__ __launch_bounds__(256) void transpose_k(const float* __restrict__ in,
                                                   u16* __restrict__ out,
                                                   int R, int Cc) {
  __shared__ float tile[32][33];
  const size_t base = (size_t)blockIdx.z * R * Cc;
  const int r0 = blockIdx.x * 32, c0 = blockIdx.y * 32;
  const int tx = threadIdx.x & 31, ty = threadIdx.x >> 5;
  const float* ip = in + base;
  u16* op = out + base;
#pragma unroll
  for (int i = 0; i < 32; i += 8)
    tile[ty + i][tx] = ip[(size_t)(r0 + ty + i) * Cc + c0 + tx];
  __syncthreads();
#pragma unroll
  for (int i = 0; i < 32; i += 8)
    op[(size_t)(c0 + ty + i) * R + r0 + tx] = f2bf(tile[tx][ty + i]);
}

// ---------------- GEMM: C[M][N] = A[M][K] * Bt[N][K]^T, epilogues ----------
// MODE 0: scatter to q[B,H,T,64] (pre-scaled), K' frag-order, V' frag-order
// MODE 1: out0(f32) = acc + bias[n] + resid[m][n]      (Wo proj + residual)
// MODE 2: out0(bf16) = relu(acc + bias[n])             (MLP up)
// MODE 3: out0(f32) = acc + bias[n] + resid[m][n]      (MLP down + residual)
template <int MODE>
__global__ __launch_bounds__(256, 3) void gemm_k(
    const u16* __restrict__ A, const u16* __restrict__ Bt,
    const float* __restrict__ bias, const float* __restrict__ resid,
    void* __restrict__ out0, void* __restrict__ out1, void* __restrict__ out2,
    int M, int N, int K) {
  __shared__ u16 As[128 * 32];   // unpadded: required by global_load_lds layout
  __shared__ u16 Bs[128 * 32];
  const int tid = threadIdx.x;
  const int lane = tid & 63;
  const int w = tid >> 6;
  const int wm = w & 1, wn = w >> 1;        // 2x2 wave grid, 64x64 per wave
  const int l15 = lane & 15, lq = lane >> 4;
  const int m0 = blockIdx.x * 128, n0 = blockIdx.y * 128;
  const int srow = lane >> 2, scol = (lane & 3) * 8;

  f32x4 acc[4][4] = {};

  // wave w stages As rows [w*32, w*32+32) and Bs rows [w*32, w*32+32)
  const u16* gA0 = A  + (size_t)(m0 + w * 32 + srow) * K + scol;
  const u16* gA1 = gA0 + (size_t)16 * K;
  const u16* gB0 = Bt + (size_t)(n0 + w * 32 + srow) * K + scol;
  const u16* gB1 = gB0 + (size_t)16 * K;
  u16* lA0 = &As[(w * 32) * 32];
  u16* lA1 = &As[(w * 32 + 16) * 32];
  u16* lB0 = &Bs[(w * 32) * 32];
  u16* lB1 = &Bs[(w * 32 + 16) * 32];

  for (int k0 = 0; k0 < K; k0 += 32) {
    __syncthreads();
    stage16(gA0 + k0, lA0, lane);
    stage16(gA1 + k0, lA1, lane);
    stage16(gB0 + k0, lB0, lane);
    stage16(gB1 + k0, lB1, lane);
    __syncthreads();   // drains vmcnt: staged data visible
    bf16x8 af[4], bfr[4];
#pragma unroll
    for (int i = 0; i < 4; ++i)
      af[i] = *(const bf16x8*)&As[(wm * 64 + i * 16 + l15) * 32 + lq * 8];
#pragma unroll
    for (int j = 0; j < 4; ++j)
      bfr[j] = *(const bf16x8*)&Bs[(wn * 64 + j * 16 + l15) * 32 + lq * 8];
#pragma unroll
    for (int i = 0; i < 4; ++i)
#pragma unroll
      for (int j = 0; j < 4; ++j)
        acc[i][j] = __builtin_amdgcn_mfma_f32_16x16x32_bf16(af[i], bfr[j], acc[i][j], 0, 0, 0);
  }

#pragma unroll
  for (int i = 0; i < 4; ++i) {
    const int mbase = m0 + wm * 64 + i * 16 + lq * 4;   // C/D row = lq*4+r
#pragma unroll
    for (int j = 0; j < 4; ++j) {
      const int ncol = n0 + wn * 64 + j * 16 + l15;     // C/D col = l15
#pragma unroll
      for (int r = 0; r < 4; ++r) {
        const float v = acc[i][j][r];
        const int m = mbase + r;
        if (MODE == 0) {
          const int which = ncol >> 10;
          const int hh = (ncol >> 6) & 15;
          const int dd = ncol & 63;
          const int tt = m & 2047;
          const size_t bhb = (size_t)((m >> 11) * 16 + hh) * 131072;
          if (which == 0) {  // q row-major [bh][t][d], pre-scaled
            ((u16*)out0)[bhb + tt * 64 + dd] = f2bf(v * QSCALE);
          } else if (which == 1) {
            // K': bh*131072 + jg*1024 + kk*512 + lane*8 + e
            //   jg=t/16, kk=d/32, lane=((d%32)/8)*16 + t%16, e=d%8
            ((u16*)out1)[bhb + (tt >> 4) * 1024 + (dd >> 5) * 512 +
                         ((((dd & 31) >> 3) * 16 + (tt & 15)) << 3) + (dd & 7)] = f2bf(v);
          } else {
            // V': bh*131072 + dt*32768 + jg*256 + lane*4 + i
            //   dt=d/16, jg=t/16, lane=(d%16) + ((t%16)/4)*16, i=t%4
            ((u16*)out2)[bhb + (dd >> 4) * 32768 + (tt >> 4) * 256 +
                         (((dd & 15) + (((tt >> 2) & 3)) * 16) << 2) + (tt & 3)] = f2bf(v);
          }
        } else if (MODE == 1 || MODE == 3) {
          ((float*)out0)[(size_t)m * N + ncol] =
              v + bias[ncol] + resid[(size_t)m * N + ncol];
        } else {
          const float t2 = v + bias[ncol];
          ((u16*)out0)[(size_t)m * N + ncol] = f2bf(t2 > 0.0f ? t2 : 0.0f);
        }
      }
    }
  }
}

// ---------------- causal flash attention (fully coalesced hot loop) --------
// q (pre-scaled, exp2 domain): [BH][2048][64] bf16 row-major.
// k: K' frag order — subtile jg load = kC + jg*1024 (+512 for kk=1), 1KB/wave.
// v: V' frag order — (dt,jg) load = vC + dt*32768 + jg*256, 512B/wave.
// attn out: [B][2048][1024] bf16. Block = (bh, 64 Q rows), 4 independent waves.
// S^T = K·Q^T: C/D layout of S^T IS the K=16 B-frag layout, so P feeds
// O^T = V^T·P^T with zero cross-lane movement. No max-tracking (scores
// bounded, diagonal guarantees l>=1).
__global__ __launch_bounds__(256) void flash_k(const u16* __restrict__ q,
                                               const u16* __restrict__ k,
                                               const u16* __restrict__ vt,
                                               u16* __restrict__ attn) {
  const int bh = blockIdx.x;                 // XCD affinity: bh%8
  const int qblk = 31 - blockIdx.y;          // longest blocks dispatch first
  const int bb = bh >> 4, hh = bh & 15;
  const int tid = threadIdx.x;
  const int lane = tid & 63, wid = tid >> 6;
  const int l15 = lane & 15, lq = lane >> 4;
  const int q0w = qblk * 64 + wid * 16;      // this wave's Q-row base

  // Q B-frags (n = qrow = l15): Q[q0w+l15][lq*8 .. +7], [+32 ..]  (once)
  const u16* qrow = q + ((size_t)bh * 2048 + q0w + l15) * 64 + lq * 8;
  const bf16x8 qb0 = *(const bf16x8*)qrow;
  const bf16x8 qb1 = *(const bf16x8*)(qrow + 32);

  // coalesced fragment stream bases
  const u16* kC = k + (size_t)bh * 131072 + lane * 8;    // + jg*1024 (+512 kk=1)
  const u16* vC = vt + (size_t)bh * 131072 + lane * 4;   // + dt*32768 + jg*256

  f32x4 o[4] = {};    // o[dt]: row = d_local = lq*4+r, col = qrow = l15
  float l_acc = 0.0f; // per-lane partial of row l15's softmax denominator

  // ---- main loop: all full (unmasked) 16-key subtiles ----
#pragma unroll 4
  for (int j0 = 0; j0 < q0w; j0 += 16) {
    const u16* kp = kC + j0 * 64;            // jg*1024 = j0*64
    f32x4 st = {};
    st = __builtin_amdgcn_mfma_f32_16x16x32_bf16(*(const bf16x8*)kp, qb0, st, 0, 0, 0);
    st = __builtin_amdgcn_mfma_f32_16x16x32_bf16(*(const bf16x8*)(kp + 512), qb1, st, 0, 0, 0);

    float p0 = exp2f(st[0]), p1 = exp2f(st[1]);
    float p2 = exp2f(st[2]), p3 = exp2f(st[3]);
    l_acc += (p0 + p1) + (p2 + p3);
    s16x4 pf;
    pf[0] = (short)f2bf_fast(p0); pf[1] = (short)f2bf_fast(p1);
    pf[2] = (short)f2bf_fast(p2); pf[3] = (short)f2bf_fast(p3);

#pragma unroll
    for (int dt = 0; dt < 4; ++dt) {
      const s16x4 va = *(const s16x4*)(vC + dt * 32768 + j0 * 16);   // jg*256
      o[dt] = mfma_pv(va, pf, o[dt]);
    }
  }

  // ---- diagonal subtile (j0 == q0w), causal-masked ----
  {
    const int j0 = q0w;
    const u16* kp = kC + j0 * 64;
    f32x4 st = {};
    st = __builtin_amdgcn_mfma_f32_16x16x32_bf16(*(const bf16x8*)kp, qb0, st, 0, 0, 0);
    st = __builtin_amdgcn_mfma_f32_16x16x32_bf16(*(const bf16x8*)(kp + 512), qb1, st, 0, 0, 0);
#pragma unroll
    for (int r = 0; r < 4; ++r)
      if (lq * 4 + r > l15) st[r] = -1e30f;

    float p0 = exp2f(st[0]), p1 = exp2f(st[1]);
    float p2 = exp2f(st[2]), p3 = exp2f(st[3]);
    l_acc += (p0 + p1) + (p2 + p3);
    s16x4 pf;
    pf[0] = (short)f2bf_fast(p0); pf[1] = (short)f2bf_fast(p1);
    pf[2] = (short)f2bf_fast(p2); pf[3] = (short)f2bf_fast(p3);

#pragma unroll
    for (int dt = 0; dt < 4; ++dt) {
      const s16x4 va = *(const s16x4*)(vC + dt * 32768 + j0 * 16);
      o[dt] = mfma_pv(va, pf, o[dt]);
    }
  }

  // row-sum: lanes sharing l15 differ in lane bits 4-5
  l_acc += __shfl_xor(l_acc, 16);
  l_acc += __shfl_xor(l_acc, 32);
  const float rl = 1.0f / l_acc;

  // write: row i = q0w+l15; d = dt*16 + lq*4 + r  (4 consecutive bf16 per dt)
  u16* op = attn + ((size_t)bb * 2048 + q0w + l15) * 1024 + hh * 64 + lq * 4;
#pragma unroll
  for (int dt = 0; dt < 4; ++dt) {
    union { s16x4 v; u16 a[4]; } pk;
#pragma unroll
    for (int r = 0; r < 4; ++r) pk.a[r] = f2bf(o[dt][r] * rl);
    *(s16x4*)(op + dt * 16) = pk.v;
  }
}

// ---------------------------------------------------------------------------
extern "C" void kernel_launch(void* const* d_in, const int* in_sizes, int n_in,
                              void* d_out, int out_size, void* d_ws, size_t ws_size,
                              hipStream_t stream) {
  const float* x   = (const float*)d_in[0];
  const float* Wq  = (const float*)d_in[1];
  const float* Wk  = (const float*)d_in[2];
  const float* Wv  = (const float*)d_in[3];
  const float* Wo  = (const float*)d_in[4];
  const float* bo  = (const float*)d_in[5];
  const float* W1  = (const float*)d_in[6];
  const float* b1  = (const float*)d_in[7];
  const float* W2  = (const float*)d_in[8];
  const float* b2  = (const float*)d_in[9];
  const float* g1  = (const float*)d_in[10];
  const float* be1 = (const float*)d_in[11];
  const float* g2  = (const float*)d_in[12];
  const float* be2 = (const float*)d_in[13];
  float* out = (float*)d_out;

  char* ws = (char*)d_ws;
  u16* Wqkv_t = (u16*)(ws + 0);            //  6 MiB  [3072][1024]
  u16* Wo_t   = (u16*)(ws + 6291456);      //  2 MiB  [1024][1024]
  u16* W1_t   = (u16*)(ws + 8388608);      //  8 MiB  [4096][1024]
  u16* W2_t   = (u16*)(ws + 16777216);     //  8 MiB  [1024][4096]
  u16* hbuf   = (u16*)(ws + 25165824);     // 16 MiB  [8192][1024] (LN out, reused)
  float* x2   = (float*)(ws + 41943040);   // 32 MiB  [8192][1024] f32 mid residual
  u16* vtb    = (u16*)(ws + 41943040);     // 16 MiB  V' frag order, overlaps x2:
                                           //   vtb dead before gemm<1> writes x2
  u16* qb     = (u16*)(ws + 75497472);     // 16 MiB  [64][2048][64]
  u16* kb     = (u16*)(ws + 92274688);     // 16 MiB  K' frag order
  u16* attnb  = (u16*)(ws + 109051904);    // 16 MiB  [8192][1024]
  u16* a1     = (u16*)(ws + 75497472);     // 64 MiB  [8192][4096], reuses qb/kb/attnb

  dim3 blk(256);

  // weights -> bf16, transposed to [N][K]
  transpose_k<<<dim3(32, 2, 16),  blk, 0, stream>>>(Wq, Wqkv_t,            1024, 64);
  transpose_k<<<dim3(32, 2, 16),  blk, 0, stream>>>(Wk, Wqkv_t + 1048576,  1024, 64);
  transpose_k<<<dim3(32, 2, 16),  blk, 0, stream>>>(Wv, Wqkv_t + 2097152,  1024, 64);
  transpose_k<<<dim3(32, 32, 1),  blk, 0, stream>>>(Wo, Wo_t,              1024, 1024);
  transpose_k<<<dim3(32, 128, 1), blk, 0, stream>>>(W1, W1_t,              1024, 4096);
  transpose_k<<<dim3(128, 32, 1), blk, 0, stream>>>(W2, W2_t,              4096, 1024);

  // LN1
  ln_k<<<8192, blk, 0, stream>>>(x, g1, be1, hbuf);
  // QKV projection with fragment-order scatter epilogue (q pre-scaled)
  gemm_k<0><<<dim3(64, 24), blk, 0, stream>>>(hbuf, Wqkv_t, nullptr, nullptr,
                                              qb, kb, vtb, 8192, 3072, 1024);
  // causal flash attention
  flash_k<<<dim3(64, 32), blk, 0, stream>>>(qb, kb, vtb, attnb);
  // output projection + bias + residual -> x2 (f32; overwrites dead vtb)
  gemm_k<1><<<dim3(64, 8), blk, 0, stream>>>(attnb, Wo_t, bo, x,
                                             x2, nullptr, nullptr, 8192, 1024, 1024);
  // LN2
  ln_k<<<8192, blk, 0, stream>>>(x2, g2, be2, hbuf);
  // MLP up + relu
  gemm_k<2><<<dim3(64, 32), blk, 0, stream>>>(hbuf, W1_t, b1, nullptr,
                                              a1, nullptr, nullptr, 8192, 4096, 1024);
  // MLP down + bias + residual -> out (f32)
  gemm_k<3><<<dim3(64, 8), blk, 0, stream>>>(a1, W2_t, b2, x2,
                                             out, nullptr, nullptr, 8192, 1024, 4096);
}

// Round 8
// 529.815 us; speedup vs baseline: 1.5403x; 1.0114x over previous
//
#include <hip/hip_runtime.h>
#include <cstdint>
#include <cstddef>

// ---------------------------------------------------------------------------
// Transformer block, MI355X bf16 MFMA implementation.
// R8 = R7 + flash exp2f() replaced with raw v_exp_f32 (libm exp2f without
// -ffast-math expands to ~30 VALU insts; counters showed ~148 VALU/iter).
// Everything else unchanged from R7 (535.9 us, flash 116 us).
// ---------------------------------------------------------------------------

typedef unsigned short u16;
typedef __attribute__((ext_vector_type(8))) __bf16 bf16x8;   // MFMA A/B frag K=32
typedef __attribute__((ext_vector_type(4))) short s16x4;     // MFMA A/B frag K=16
typedef __attribute__((ext_vector_type(4))) float f32x4;     // MFMA C/D frag

#if defined(__has_builtin)
#if __has_builtin(__builtin_amdgcn_global_load_lds)
#define HAS_GLL 1
#endif
#endif

// attention scale 1/sqrt(64) folded with log2(e) so softmax runs in exp2 domain
#define QSCALE 0.18033688011112042f

__device__ __forceinline__ u16 f2bf(float f) {
  union { float f; unsigned int u; } c; c.f = f;
  unsigned int u = c.u;
  u += 0x7FFFu + ((u >> 16) & 1u);   // round-to-nearest-even
  return (u16)(u >> 16);
}
__device__ __forceinline__ u16 f2bf_fast(float f) {   // round-half-up, 2 insts
  union { float f; unsigned int u; } c; c.f = f;
  return (u16)((c.u + 0x8000u) >> 16);
}

// hardware exp2: one v_exp_f32 (transcendental pipe). libm exp2f is ~30 insts
// without -ffast-math — this was flash's VALU hog (R7 counters).
__device__ __forceinline__ float fexp2(float x) {
#if defined(__HIP_DEVICE_COMPILE__)
#if defined(__has_builtin) && __has_builtin(__builtin_amdgcn_exp2f)
  return __builtin_amdgcn_exp2f(x);
#else
  float r;
  asm("v_exp_f32 %0, %1" : "=v"(r) : "v"(x));
  return r;
#endif
#else
  return x;   // host stub, never executed
#endif
}

// K=16 bf16 MFMA (v_mfma_f32_16x16x16_bf16). Device-only; host sees a stub.
__device__ __forceinline__ f32x4 mfma_pv(s16x4 a, s16x4 b, f32x4 c) {
#if defined(__HIP_DEVICE_COMPILE__)
#if defined(__has_builtin) && __has_builtin(__builtin_amdgcn_mfma_f32_16x16x16bf16_1k)
  return __builtin_amdgcn_mfma_f32_16x16x16bf16_1k(a, b, c, 0, 0, 0);
#else
  f32x4 d;
  asm volatile("v_mfma_f32_16x16x16_bf16 %0, %1, %2, %3"
               : "=v"(d) : "v"(a), "v"(b), "v"(c));
  return d;
#endif
#else
  (void)a; (void)b;
  return c;   // host stub, never executed
#endif
}

// async 16B/lane global->LDS stage; l must be wave-uniform, lane i lands at l+16*i
__device__ __forceinline__ void stage16(const u16* g, u16* l, int lane) {
#ifdef HAS_GLL
  __builtin_amdgcn_global_load_lds(
      (const __attribute__((address_space(1))) uint32_t*)(g),
      (__attribute__((address_space(3))) uint32_t*)(l), 16, 0, 0);
#else
  *(int4*)(l + lane * 8) = *(const int4*)g;
#endif
}

// ---------------- LayerNorm: fp32 [rows][1024] -> bf16 [rows][1024] --------
__global__ __launch_bounds__(256) void ln_k(const float* __restrict__ x,
                                            const float* __restrict__ g,
                                            const float* __restrict__ be,
                                            u16* __restrict__ out) {
  const int row = blockIdx.x;
  const int t = threadIdx.x;
  const float4 v = ((const float4*)(x + (size_t)row * 1024))[t];
  float s = v.x + v.y + v.z + v.w;
  float s2 = v.x * v.x + v.y * v.y + v.z * v.z + v.w * v.w;
#pragma unroll
  for (int off = 32; off > 0; off >>= 1) {
    s += __shfl_down(s, off);
    s2 += __shfl_down(s2, off);
  }
  __shared__ float red[8];
  if ((t & 63) == 0) { red[t >> 6] = s; red[4 + (t >> 6)] = s2; }
  __syncthreads();
  const float ts = red[0] + red[1] + red[2] + red[3];
  const float ts2 = red[4] + red[5] + red[6] + red[7];
  const float mu = ts * (1.0f / 1024.0f);
  const float var = ts2 * (1.0f / 1024.0f) - mu * mu;
  const float rstd = rsqrtf(var + 1e-5f);
  const float4 gv = ((const float4*)g)[t];
  const float4 bv = ((const float4*)be)[t];
  u16* op = out + (size_t)row * 1024 + t * 4;
  op[0] = f2bf((v.x - mu) * rstd * gv.x + bv.x);
  op[1] = f2bf((v.y - mu) * rstd * gv.y + bv.y);
  op[2] = f2bf((v.z - mu) * rstd * gv.z + bv.z);
  op[3] = f2bf((v.w - mu) * rstd * gv.w + bv.w);
}

// ------------- batched transpose fp32 [b][R][C] -> bf16 [b][C][R] ----------
__global__ __launch_bounds__(256) void transpose_k(const float* __restrict__ in,
                                                   u16* __restrict__ out,
                                                   int R, int Cc) {
  __shared__ float tile[32][33];
  const size_t base = (size_t)blockIdx.z * R * Cc;
  const int r0 = blockIdx.x * 32, c0 = blockIdx.y * 32;
  const int tx = threadIdx.x & 31, ty = threadIdx.x >> 5;
  const float* ip = in + base;
  u16* op = out + base;
#pragma unroll
  for (int i = 0; i < 32; i += 8)
    tile[ty + i][tx] = ip[(size_t)(r0 + ty + i) * Cc + c0 + tx];
  __syncthreads();
#pragma unroll
  for (int i = 0; i < 32; i += 8)
    op[(size_t)(c0 + ty + i) * R + r0 + tx] = f2bf(tile[tx][ty + i]);
}

// ---------------- GEMM: C[M][N] = A[M][K] * Bt[N][K]^T, epilogues ----------
// MODE 0: scatter to q[B,H,T,64] (pre-scaled), K' frag-order, V' frag-order
// MODE 1: out0(f32) = acc + bias[n] + resid[m][n]      (Wo proj + residual)
// MODE 2: out0(bf16) = relu(acc + bias[n])             (MLP up)
// MODE 3: out0(f32) = acc + bias[n] + resid[m][n]      (MLP down + residual)
template <int MODE>
__global__ __launch_bounds__(256, 3) void gemm_k(
    const u16* __restrict__ A, const u16* __restrict__ Bt,
    const float* __restrict__ bias, const float* __restrict__ resid,
    void* __restrict__ out0, void* __restrict__ out1, void* __restrict__ out2,
    int M, int N, int K) {
  __shared__ u16 As[128 * 32];   // unpadded: required by global_load_lds layout
  __shared__ u16 Bs[128 * 32];
  const int tid = threadIdx.x;
  const int lane = tid & 63;
  const int w = tid >> 6;
  const int wm = w & 1, wn = w >> 1;        // 2x2 wave grid, 64x64 per wave
  const int l15 = lane & 15, lq = lane >> 4;
  const int m0 = blockIdx.x * 128, n0 = blockIdx.y * 128;
  const int srow = lane >> 2, scol = (lane & 3) * 8;

  f32x4 acc[4][4] = {};

  // wave w stages As rows [w*32, w*32+32) and Bs rows [w*32, w*32+32)
  const u16* gA0 = A  + (size_t)(m0 + w * 32 + srow) * K + scol;
  const u16* gA1 = gA0 + (size_t)16 * K;
  const u16* gB0 = Bt + (size_t)(n0 + w * 32 + srow) * K + scol;
  const u16* gB1 = gB0 + (size_t)16 * K;
  u16* lA0 = &As[(w * 32) * 32];
  u16* lA1 = &As[(w * 32 + 16) * 32];
  u16* lB0 = &Bs[(w * 32) * 32];
  u16* lB1 = &Bs[(w * 32 + 16) * 32];

  for (int k0 = 0; k0 < K; k0 += 32) {
    __syncthreads();
    stage16(gA0 + k0, lA0, lane);
    stage16(gA1 + k0, lA1, lane);
    stage16(gB0 + k0, lB0, lane);
    stage16(gB1 + k0, lB1, lane);
    __syncthreads();   // drains vmcnt: staged data visible
    bf16x8 af[4], bfr[4];
#pragma unroll
    for (int i = 0; i < 4; ++i)
      af[i] = *(const bf16x8*)&As[(wm * 64 + i * 16 + l15) * 32 + lq * 8];
#pragma unroll
    for (int j = 0; j < 4; ++j)
      bfr[j] = *(const bf16x8*)&Bs[(wn * 64 + j * 16 + l15) * 32 + lq * 8];
#pragma unroll
    for (int i = 0; i < 4; ++i)
#pragma unroll
      for (int j = 0; j < 4; ++j)
        acc[i][j] = __builtin_amdgcn_mfma_f32_16x16x32_bf16(af[i], bfr[j], acc[i][j], 0, 0, 0);
  }

#pragma unroll
  for (int i = 0; i < 4; ++i) {
    const int mbase = m0 + wm * 64 + i * 16 + lq * 4;   // C/D row = lq*4+r
#pragma unroll
    for (int j = 0; j < 4; ++j) {
      const int ncol = n0 + wn * 64 + j * 16 + l15;     // C/D col = l15
#pragma unroll
      for (int r = 0; r < 4; ++r) {
        const float v = acc[i][j][r];
        const int m = mbase + r;
        if (MODE == 0) {
          const int which = ncol >> 10;
          const int hh = (ncol >> 6) & 15;
          const int dd = ncol & 63;
          const int tt = m & 2047;
          const size_t bhb = (size_t)((m >> 11) * 16 + hh) * 131072;
          if (which == 0) {  // q row-major [bh][t][d], pre-scaled
            ((u16*)out0)[bhb + tt * 64 + dd] = f2bf(v * QSCALE);
          } else if (which == 1) {
            // K': bh*131072 + jg*1024 + kk*512 + lane*8 + e
            //   jg=t/16, kk=d/32, lane=((d%32)/8)*16 + t%16, e=d%8
            ((u16*)out1)[bhb + (tt >> 4) * 1024 + (dd >> 5) * 512 +
                         ((((dd & 31) >> 3) * 16 + (tt & 15)) << 3) + (dd & 7)] = f2bf(v);
          } else {
            // V': bh*131072 + dt*32768 + jg*256 + lane*4 + i
            //   dt=d/16, jg=t/16, lane=(d%16) + ((t%16)/4)*16, i=t%4
            ((u16*)out2)[bhb + (dd >> 4) * 32768 + (tt >> 4) * 256 +
                         (((dd & 15) + (((tt >> 2) & 3)) * 16) << 2) + (tt & 3)] = f2bf(v);
          }
        } else if (MODE == 1 || MODE == 3) {
          ((float*)out0)[(size_t)m * N + ncol] =
              v + bias[ncol] + resid[(size_t)m * N + ncol];
        } else {
          const float t2 = v + bias[ncol];
          ((u16*)out0)[(size_t)m * N + ncol] = f2bf(t2 > 0.0f ? t2 : 0.0f);
        }
      }
    }
  }
}

// ---------------- causal flash attention (fully coalesced hot loop) --------
// q (pre-scaled, exp2 domain): [BH][2048][64] bf16 row-major.
// k: K' frag order — subtile jg load = kC + jg*1024 (+512 for kk=1), 1KB/wave.
// v: V' frag order — (dt,jg) load = vC + dt*32768 + jg*256, 512B/wave.
// attn out: [B][2048][1024] bf16. Block = (bh, 64 Q rows), 4 independent waves.
// S^T = K·Q^T: C/D layout of S^T IS the K=16 B-frag layout, so P feeds
// O^T = V^T·P^T with zero cross-lane movement. No max-tracking (scores
// bounded, diagonal guarantees l>=1).
__global__ __launch_bounds__(256) void flash_k(const u16* __restrict__ q,
                                               const u16* __restrict__ k,
                                               const u16* __restrict__ vt,
                                               u16* __restrict__ attn) {
  const int bh = blockIdx.x;                 // XCD affinity: bh%8
  const int qblk = 31 - blockIdx.y;          // longest blocks dispatch first
  const int bb = bh >> 4, hh = bh & 15;
  const int tid = threadIdx.x;
  const int lane = tid & 63, wid = tid >> 6;
  const int l15 = lane & 15, lq = lane >> 4;
  const int q0w = qblk * 64 + wid * 16;      // this wave's Q-row base

  // Q B-frags (n = qrow = l15): Q[q0w+l15][lq*8 .. +7], [+32 ..]  (once)
  const u16* qrow = q + ((size_t)bh * 2048 + q0w + l15) * 64 + lq * 8;
  const bf16x8 qb0 = *(const bf16x8*)qrow;
  const bf16x8 qb1 = *(const bf16x8*)(qrow + 32);

  // coalesced fragment stream bases
  const u16* kC = k + (size_t)bh * 131072 + lane * 8;    // + jg*1024 (+512 kk=1)
  const u16* vC = vt + (size_t)bh * 131072 + lane * 4;   // + dt*32768 + jg*256

  f32x4 o[4] = {};    // o[dt]: row = d_local = lq*4+r, col = qrow = l15
  float l_acc = 0.0f; // per-lane partial of row l15's softmax denominator

  // ---- main loop: all full (unmasked) 16-key subtiles ----
#pragma unroll 4
  for (int j0 = 0; j0 < q0w; j0 += 16) {
    const u16* kp = kC + j0 * 64;            // jg*1024 = j0*64
    f32x4 st = {};
    st = __builtin_amdgcn_mfma_f32_16x16x32_bf16(*(const bf16x8*)kp, qb0, st, 0, 0, 0);
    st = __builtin_amdgcn_mfma_f32_16x16x32_bf16(*(const bf16x8*)(kp + 512), qb1, st, 0, 0, 0);

    float p0 = fexp2(st[0]), p1 = fexp2(st[1]);
    float p2 = fexp2(st[2]), p3 = fexp2(st[3]);
    l_acc += (p0 + p1) + (p2 + p3);
    s16x4 pf;
    pf[0] = (short)f2bf_fast(p0); pf[1] = (short)f2bf_fast(p1);
    pf[2] = (short)f2bf_fast(p2); pf[3] = (short)f2bf_fast(p3);

#pragma unroll
    for (int dt = 0; dt < 4; ++dt) {
      const s16x4 va = *(const s16x4*)(vC + dt * 32768 + j0 * 16);   // jg*256
      o[dt] = mfma_pv(va, pf, o[dt]);
    }
  }

  // ---- diagonal subtile (j0 == q0w), causal-masked ----
  {
    const int j0 = q0w;
    const u16* kp = kC + j0 * 64;
    f32x4 st = {};
    st = __builtin_amdgcn_mfma_f32_16x16x32_bf16(*(const bf16x8*)kp, qb0, st, 0, 0, 0);
    st = __builtin_amdgcn_mfma_f32_16x16x32_bf16(*(const bf16x8*)(kp + 512), qb1, st, 0, 0, 0);
#pragma unroll
    for (int r = 0; r < 4; ++r)
      if (lq * 4 + r > l15) st[r] = -1e30f;

    float p0 = fexp2(st[0]), p1 = fexp2(st[1]);
    float p2 = fexp2(st[2]), p3 = fexp2(st[3]);
    l_acc += (p0 + p1) + (p2 + p3);
    s16x4 pf;
    pf[0] = (short)f2bf_fast(p0); pf[1] = (short)f2bf_fast(p1);
    pf[2] = (short)f2bf_fast(p2); pf[3] = (short)f2bf_fast(p3);

#pragma unroll
    for (int dt = 0; dt < 4; ++dt) {
      const s16x4 va = *(const s16x4*)(vC + dt * 32768 + j0 * 16);
      o[dt] = mfma_pv(va, pf, o[dt]);
    }
  }

  // row-sum: lanes sharing l15 differ in lane bits 4-5
  l_acc += __shfl_xor(l_acc, 16);
  l_acc += __shfl_xor(l_acc, 32);
  const float rl = 1.0f / l_acc;

  // write: row i = q0w+l15; d = dt*16 + lq*4 + r  (4 consecutive bf16 per dt)
  u16* op = attn + ((size_t)bb * 2048 + q0w + l15) * 1024 + hh * 64 + lq * 4;
#pragma unroll
  for (int dt = 0; dt < 4; ++dt) {
    union { s16x4 v; u16 a[4]; } pk;
#pragma unroll
    for (int r = 0; r < 4; ++r) pk.a[r] = f2bf(o[dt][r] * rl);
    *(s16x4*)(op + dt * 16) = pk.v;
  }
}

// ---------------------------------------------------------------------------
extern "C" void kernel_launch(void* const* d_in, const int* in_sizes, int n_in,
                              void* d_out, int out_size, void* d_ws, size_t ws_size,
                              hipStream_t stream) {
  const float* x   = (const float*)d_in[0];
  const float* Wq  = (const float*)d_in[1];
  const float* Wk  = (const float*)d_in[2];
  const float* Wv  = (const float*)d_in[3];
  const float* Wo  = (const float*)d_in[4];
  const float* bo  = (const float*)d_in[5];
  const float* W1  = (const float*)d_in[6];
  const float* b1  = (const float*)d_in[7];
  const float* W2  = (const float*)d_in[8];
  const float* b2  = (const float*)d_in[9];
  const float* g1  = (const float*)d_in[10];
  const float* be1 = (const float*)d_in[11];
  const float* g2  = (const float*)d_in[12];
  const float* be2 = (const float*)d_in[13];
  float* out = (float*)d_out;

  char* ws = (char*)d_ws;
  u16* Wqkv_t = (u16*)(ws + 0);            //  6 MiB  [3072][1024]
  u16* Wo_t   = (u16*)(ws + 6291456);      //  2 MiB  [1024][1024]
  u16* W1_t   = (u16*)(ws + 8388608);      //  8 MiB  [4096][1024]
  u16* W2_t   = (u16*)(ws + 16777216);     //  8 MiB  [1024][4096]
  u16* hbuf   = (u16*)(ws + 25165824);     // 16 MiB  [8192][1024] (LN out, reused)
  float* x2   = (float*)(ws + 41943040);   // 32 MiB  [8192][1024] f32 mid residual
  u16* vtb    = (u16*)(ws + 41943040);     // 16 MiB  V' frag order, overlaps x2:
                                           //   vtb dead before gemm<1> writes x2
  u16* qb     = (u16*)(ws + 75497472);     // 16 MiB  [64][2048][64]
  u16* kb     = (u16*)(ws + 92274688);     // 16 MiB  K' frag order
  u16* attnb  = (u16*)(ws + 109051904);    // 16 MiB  [8192][1024]
  u16* a1     = (u16*)(ws + 75497472);     // 64 MiB  [8192][4096], reuses qb/kb/attnb

  dim3 blk(256);

  // weights -> bf16, transposed to [N][K]
  transpose_k<<<dim3(32, 2, 16),  blk, 0, stream>>>(Wq, Wqkv_t,            1024, 64);
  transpose_k<<<dim3(32, 2, 16),  blk, 0, stream>>>(Wk, Wqkv_t + 1048576,  1024, 64);
  transpose_k<<<dim3(32, 2, 16),  blk, 0, stream>>>(Wv, Wqkv_t + 2097152,  1024, 64);
  transpose_k<<<dim3(32, 32, 1),  blk, 0, stream>>>(Wo, Wo_t,              1024, 1024);
  transpose_k<<<dim3(32, 128, 1), blk, 0, stream>>>(W1, W1_t,              1024, 4096);
  transpose_k<<<dim3(128, 32, 1), blk, 0, stream>>>(W2, W2_t,              4096, 1024);

  // LN1
  ln_k<<<8192, blk, 0, stream>>>(x, g1, be1, hbuf);
  // QKV projection with fragment-order scatter epilogue (q pre-scaled)
  gemm_k<0><<<dim3(64, 24), blk, 0, stream>>>(hbuf, Wqkv_t, nullptr, nullptr,
                                              qb, kb, vtb, 8192, 3072, 1024);
  // causal flash attention
  flash_k<<<dim3(64, 32), blk, 0, stream>>>(qb, kb, vtb, attnb);
  // output projection + bias + residual -> x2 (f32; overwrites dead vtb)
  gemm_k<1><<<dim3(64, 8), blk, 0, stream>>>(attnb, Wo_t, bo, x,
                                             x2, nullptr, nullptr, 8192, 1024, 1024);
  // LN2
  ln_k<<<8192, blk, 0, stream>>>(x2, g2, be2, hbuf);
  // MLP up + relu
  gemm_k<2><<<dim3(64, 32), blk, 0, stream>>>(hbuf, W1_t, b1, nullptr,
                                              a1, nullptr, nullptr, 8192, 4096, 1024);
  // MLP down + bias + residual -> out (f32)
  gemm_k<3><<<dim3(64, 8), blk, 0, stream>>>(a1, W2_t, b2, x2,
                                             out, nullptr, nullptr, 8192, 1024, 4096);
}